// Round 6
// baseline (514.322 us; speedup 1.0000x reference)
//
#include <hip/hip_runtime.h>
#include <hip/hip_bf16.h>

#define N_NODES 50000
#define N_EDGES 1600000
#define IN_F 64
#define E_F 32
#define HID 128
#define OUT_F 4

typedef __attribute__((ext_vector_type(4))) float f32x4;
typedef __attribute__((ext_vector_type(8))) short short8;
typedef __attribute__((ext_vector_type(4))) int i32x4;

__device__ inline short f2bf(float f) {
  union { float f; unsigned u; } v; v.f = f;
  unsigned r = v.u + 0x7FFFu + ((v.u >> 16) & 1u);   // round-to-nearest-even
  return (short)(r >> 16);
}
__device__ inline float bf2f(short s) {
  union { unsigned u; float f; } v; v.u = ((unsigned)(unsigned short)s) << 16;
  return v.f;
}

// -----------------------------------------------------------------------------
// Kernel 1 (rewritten): P[n] = bf16([h[n]@Wu ; h[n]@Wv]) in layout [half][col][t]
// (offset o = col*8+t <-> feature j(o) = (o&7)*16 + (o>>3)).
// No LDS at all. Thread (o, half) keeps its W-column (64 floats) in VGPRs;
// the h-row load address is wave-UNIFORM -> compiler emits s_load, h values
// become SGPR broadcast operands to v_fma. Old version issued 5 ds_reads per
// 4 FMAs (LDS-issue-bound, ~300+ us); this is pure VALU, ~6400 FMA/thread.
// -----------------------------------------------------------------------------
__global__ __launch_bounds__(256) void node_pre(const float* __restrict__ h,
                                                const float* __restrict__ W1,
                                                short* __restrict__ P) {
  const int tid  = threadIdx.x;
  const int o    = tid & 127;                 // storage offset within half
  const int half = tid >> 7;                  // 0 = u-part, 1 = v-part
  const int j    = (o & 7) * 16 + (o >> 3);   // math feature column

  float wreg[64];                             // this thread's W column (one-time)
#pragma unroll
  for (int k = 0; k < 64; ++k) wreg[k] = W1[(half * 64 + k) * 128 + j];

  const int n0 = blockIdx.x * 49;
  const int n1 = min(n0 + 49, N_NODES);
  for (int n = n0; n < n1; ++n) {
    const float* __restrict__ hrow = h + (size_t)n * IN_F;   // uniform address
    float a0 = 0.f, a1 = 0.f, a2 = 0.f, a3 = 0.f;            // 4 chains for ILP
#pragma unroll
    for (int k = 0; k < 64; k += 4) {
      a0 = fmaf(hrow[k    ], wreg[k    ], a0);
      a1 = fmaf(hrow[k + 1], wreg[k + 1], a1);
      a2 = fmaf(hrow[k + 2], wreg[k + 2], a2);
      a3 = fmaf(hrow[k + 3], wreg[k + 3], a3);
    }
    P[(size_t)n * 256 + half * 128 + o] = f2bf((a0 + a1) + (a2 + a3));
  }
}

// -----------------------------------------------------------------------------
// Kernel 2 (rewritten): fused edge MLP, NO LDS, NO barriers.
//   Each wave owns a 16-edge tile; A-fragments for e@We are loaded DIRECTLY
//   from global: lane (col,rowg) reads ef[e0+col][rowg*8 .. +7] (2 x f32x4;
//   the 64 lanes exactly tile the 2 KB edge-slab -> fully coalesced), f2bf
//   in-register. Waves are independent -> no __syncthreads serialization,
//   VMEM latency hides under other waves.
//   MFMA 16x16x32 layouts (m89-verified): A row=lane&15,k=8*(lane>>4)+i;
//   B col=lane&15 same k; D col=lane&15,row=4*(lane>>4)+reg.
//   P gathers: one short8 (16 B) per edge-endpoint-half ([half][col][t] layout).
// -----------------------------------------------------------------------------
#define TPW 8   // tiles (16 edges) per wave
__global__ __launch_bounds__(256) void edge_mlp(
    const float* __restrict__ ef, const int* __restrict__ src,
    const int* __restrict__ dst, const float* __restrict__ W1,
    const float* __restrict__ b1, const float* __restrict__ W2,
    const float* __restrict__ b2, const short* __restrict__ P,
    float* __restrict__ out) {
  const int tid  = threadIdx.x;
  const int lane = tid & 63;
  const int wid  = tid >> 6;
  const int col  = lane & 15;     // feat (N) index within 16-slab / A-row
  const int rowg = lane >> 4;     // k group / D row group

  // ---- loop-invariant register state ----
  short8 bfrag[8];                // We (32x128) bf16 B-fragments, one per 16-feat slab
#pragma unroll
  for (int t = 0; t < 8; ++t) {
#pragma unroll
    for (int i = 0; i < 8; ++i) {
      const float f = W1[(2 * IN_F + rowg * 8 + i) * HID + t * 16 + col];
      bfrag[t][i] = f2bf(f);
    }
  }
  float b1r[8];
  f32x4 w2r[8];
#pragma unroll
  for (int t = 0; t < 8; ++t) {
    b1r[t] = b1[t * 16 + col];
    w2r[t] = ((const f32x4*)W2)[t * 16 + col];   // W2 row (4 floats)
  }
  const f32x4 b2r = *((const f32x4*)b2);

  const int tile0 = (blockIdx.x * 4 + wid) * TPW;   // wave's first 16-edge tile

  for (int tt = 0; tt < TPW; ++tt) {
    const int e0    = (tile0 + tt) * 16;
    const int ebase = e0 + rowg * 4;

    // ---- edge indices for the epilogue gathers (issued early) ----
    const i32x4 se = __builtin_nontemporal_load((const i32x4*)(src + ebase));
    const i32x4 de = __builtin_nontemporal_load((const i32x4*)(dst + ebase));

    // ---- A fragment straight from global (32 B/lane, wave tiles 2 KB) ----
    const f32x4* ea = (const f32x4*)(ef + (size_t)(e0 + col) * E_F + rowg * 8);
    const f32x4 a0 = __builtin_nontemporal_load(ea);
    const f32x4 a1 = __builtin_nontemporal_load(ea + 1);
    short8 af;
#pragma unroll
    for (int i = 0; i < 4; ++i) af[i] = f2bf(a0[i]);
#pragma unroll
    for (int i = 0; i < 4; ++i) af[4 + i] = f2bf(a1[i]);

    // ---- 8 MFMAs: acc[t][q] = (E @ We)[edge rowg*4+q, feat t*16+col] ----
    f32x4 acc[8];
#pragma unroll
    for (int t = 0; t < 8; ++t)
      acc[t] = __builtin_amdgcn_mfma_f32_16x16x32_bf16(
          af, bfrag[t], (f32x4){0.f, 0.f, 0.f, 0.f}, 0, 0, 0);

    // ---- gather P rows (one short8 per endpoint-half), hid, relu, project ----
    const int sidx[4] = {se.x, se.y, se.z, se.w};
    const int didx[4] = {de.x, de.y, de.z, de.w};
    short8 lu[4], lv[4];
#pragma unroll
    for (int q = 0; q < 4; ++q) {          // issue all 8 gathers before consuming
      lu[q] = *(const short8*)(P + (size_t)sidx[q] * 256 + col * 8);
      lv[q] = *(const short8*)(P + (size_t)didx[q] * 256 + 128 + col * 8);
    }
    f32x4 part[4] = {(f32x4){0,0,0,0}, (f32x4){0,0,0,0},
                     (f32x4){0,0,0,0}, (f32x4){0,0,0,0}};
#pragma unroll
    for (int q = 0; q < 4; ++q) {
#pragma unroll
      for (int t = 0; t < 8; ++t) {
        float hid = acc[t][q] + bf2f(lu[q][t]) + bf2f(lv[q][t]) + b1r[t];
        hid = fmaxf(hid, 0.f);
#pragma unroll
        for (int o = 0; o < 4; ++o)
          part[q][o] = fmaf(hid, w2r[t][o], part[q][o]);
      }
    }

    // ---- reduce over the 16 col-lanes (xor<16 keeps rowg groups intact) ----
#pragma unroll
    for (int q = 0; q < 4; ++q) {
#pragma unroll
      for (int o = 0; o < 4; ++o) {
        float v = part[q][o];
        v += __shfl_xor(v, 1);
        v += __shfl_xor(v, 2);
        v += __shfl_xor(v, 4);
        v += __shfl_xor(v, 8);
        part[q][o] = v + b2r[o];
      }
    }
    if (col == 0) {
#pragma unroll
      for (int q = 0; q < 4; ++q)
        __builtin_nontemporal_store(part[q], (f32x4*)out + ebase + q);
    }
  }
}

extern "C" void kernel_launch(void* const* d_in, const int* in_sizes, int n_in,
                              void* d_out, int out_size, void* d_ws, size_t ws_size,
                              hipStream_t stream) {
  const float* h   = (const float*)d_in[0];
  const float* ef  = (const float*)d_in[1];
  const int*   src = (const int*)d_in[2];
  const int*   dst = (const int*)d_in[3];
  const float* W1  = (const float*)d_in[4];
  const float* b1  = (const float*)d_in[5];
  const float* W2  = (const float*)d_in[6];
  const float* b2  = (const float*)d_in[7];
  float* out = (float*)d_out;
  short* P   = (short*)d_ws;     // 50000 * 256 * 2 B = 25.6 MB scratch

  hipLaunchKernelGGL(node_pre, dim3((N_NODES + 48) / 49), dim3(256), 0, stream,
                     h, W1, P);
  // 100000 16-edge tiles / (4 waves * TPW) = 3125 blocks
  hipLaunchKernelGGL(edge_mlp, dim3(N_EDGES / (16 * 4 * TPW)), dim3(256), 0,
                     stream, ef, src, dst, W1, b1, W2, b2, P, out);
}